// Round 9
// baseline (57.631 us; speedup 1.0000x reference)
//
#include <hip/hip_runtime.h>

#define PRECS 1e-6f

// raw hardware transcendentals: v_exp_f32 / v_log_f32 (base-2).
// fpow(0, e>0) == 0 exactly: log2(0)=-inf -> exp2(-inf)=0.
__device__ __forceinline__ float fpow(float b, float e) {
    return __builtin_amdgcn_exp2f(e * __builtin_amdgcn_logf(b));
}

__device__ __forceinline__ float frcp(float v) {
    return __builtin_amdgcn_rcpf(v);
}

__device__ __forceinline__ float med3(float a, float b, float c) {
    return __builtin_amdgcn_fmed3f(a, b, c);
}

template <int CTRL>
__device__ __forceinline__ float dpp_mov(float v) {
    return __int_as_float(
        __builtin_amdgcn_update_dpp(0, __float_as_int(v), CTRL, 0xF, 0xF, true));
}

// sum over each 8-lane group, entirely on the VALU pipe (DPP, no LDS)
__device__ __forceinline__ float rsum8(float v) {
    v += dpp_mov<0xB1>(v);   // quad_perm [1,0,3,2]  : lane ^= 1
    v += dpp_mov<0x4E>(v);   // quad_perm [2,3,0,1]  : lane ^= 2
    v += dpp_mov<0x141>(v);  // row_half_mirror      : lane -> 7-lane within 8
    return v;
}

// 4-stage wave-specialized pipeline over 16-step blocks (one wave per SIMD).
// This revision collapses the transcendental cycles:
//   A: carries pw1 = base_W^invB. Wet steps: W' = WM*(1-powr) exactly (relu
//      provably inactive, cascade provably clamp-free) => pw1' = omr up to the
//      PRECS floor (fmax powPRECS). Dry steps: W' = W-SUME is known right
//      after SUME, so the dry pow runs PARALLEL to the powr/R_per/cascade
//      branch. Only ONE pow (powr) remains on A's carried cycle.
//   B: the carry bypasses RS entirely: S_mid = S_eq + med3(T + (R_per*iFR -
//      PE), 0, R_per*iFR), T = SM - SM*q - S_eq  — exact through all RS-clamp
//      cases; degenerates to S_eq when PE=0. RS is computed off-chain for the
//      output only. C pre-packs giFR = g*iFR and r2 = giFR*inv_SM.
__global__ __launch_bounds__(256, 1) void xaj_kernel(
    const float* __restrict__ x,     // (365, 2000, 3)
    const float* __restrict__ prm,   // (2000, 12, 8)
    float* __restrict__ out)         // (365, 2000, 5)
{
    constexpr int Nstep = 365, Ngrid = 2000;
    constexpr int xstride = Ngrid * 3;
    constexpr int K = 16;            // steps per pipeline block
    constexpr int NBLK = 23;         // 23*16 = 368 padded steps
    constexpr int NPH  = NBLK + 3;   // 26 phases (D drains at p = NBLK+2)

    const int wid  = (int)threadIdx.x >> 6;   // 0=A, 1=B, 2=C, 3=D
    const int lane = (int)threadIdx.x & 63;
    const int g = blockIdx.x * 8 + (lane >> 3);   // 250 blocks * 8 grids = 2000
    const int m = lane & 7;

    __shared__ float2 stIn[2][K][64];   // {P, PET*KE}            (C -> A)
    __shared__ float4 stA[4][K][64];    // {PE, R_per, E, -}      (A -> C,B)
    __shared__ float4 stFR[2][K][64];   // {FR, iFR, giFR, r2}    (C -> B)
    __shared__ float4 stB[2][K][64];    // {RS, FR*Sn, E, -}      (B -> D)

    const float lo[12] = {0.3f,0.0f,0.01f,0.01f,0.01f,0.09f,0.01f,0.0f,0.01f,0.01f,0.0f,0.0f};
    const float hi[12] = {2.0f,5.0f,100.0f,100.0f,200.0f,1.0f,100.0f,10.0f,0.7f,0.7f,0.998f,0.998f};
    float p[12];
    const float* pb = prm + (size_t)g * 96 + m;
#pragma unroll
    for (int i = 0; i < 12; ++i)
        p[i] = lo[i] + pb[i * 8] * (hi[i] - lo[i]);

    const float KE=p[0], B=p[1], WUM=p[2], WLM=p[3], WM=p[4], C=p[5],
                SM=p[6], EX=p[7], KI_=p[8], KG_=p[9], CI=p[10], CG=p[11];

    // loop-invariant derived constants
    const float wdm  = fmaxf(WM - WUM - WLM, 0.f);
    const float sumk = KI_ + KG_;
    const float nrm  = (1.f - PRECS) / (sumk + PRECS);
    const float KI   = (sumk < 1.f) ? KI_ : KI_ * nrm;
    const float KG   = (sumk < 1.f) ? KG_ : KG_ * nrm;
    const float expB = 1.f + B,  invB  = 1.f / expB;
    const float WMM  = WM * expB;
    const float expEX= 1.f + EX, invEX = 1.f / expEX;
    const float SMM  = SM * expEX;
    const float inv_WLM = 1.f / (WLM + PRECS);
    const float inv_WM  = 1.f / (WM  + PRECS);
    const float inv_WMM = 1.f / (WMM + PRECS);
    const float inv_SM  = 1.f / (SM  + PRECS);
    const float inv_SMM = 1.f / (SMM + PRECS);
    const float oneK = 1.f - KI - KG;
    const float omCI = 1.f - CI, omCG = 1.f - CG;
    const float CWLM = C * WLM;
    const float inv1p = 1.f / (1.f + PRECS);
    // exact floor of ratio_s when S_eq hits the SM clamp: 1 - SM*inv_SM
    const float eps2  = fmaxf(PRECS, fmaf(-SM, inv_SM, 1.f));
    const float powPRECS = fpow(PRECS, invB);   // base_W floor, propagated thru ^invB

    // -------- per-stage carried state (exclusive per wave path) --------
    float WU = 0.001f, WL = 0.001f, WD = 0.001f;          // A
    // A: carried pw1 + tail-hoisted EL helpers (functions of carried WL)
    float pw1;
    {
        const float W0 = 0.003f;
        pw1 = fpow(fmaxf(fmaf(-W0, inv_WM, 1.f), PRECS), invB);
    }
    float weC0   = fmaxf(WL - CWLM, 0.f);
    float wrC    = weC0 * frcp(1.f + weC0);
    float wlinvC = WL * inv_WLM;

    float Snc = 0.001f / oneK;                            // B: pre-oneK S
    float FRc = 0.001f, iFRc = frcp(0.001f + PRECS);      // C resolve carry
    float QI = 0.001f, QG = 0.001f;                       // D
    const float cKI = omCI * KI, cKG = omCG * KG;         // D
    const float wa = (m == 0 || m == 1) ? 0.125f : 0.f;   // D output weights
    const float wb = (m == 0 || m == 2) ? 0.125f : 0.f;
    const float wc = (m == 0 || m == 3) ? 0.125f : 0.f;
    const float wd = (m >= 4) ? 0.125f : 0.f;
    const int   col = (m < 4) ? m : 4;
    float* outp = out + (size_t)g * 5 + col;
    const size_t ostr = (size_t)Ngrid * 5;
    const float* xg = x + (size_t)g * 3;
    float Pr[K], Er[K];                                   // C load staging

    // ---------------- stage bodies ----------------
    auto ASTEP = [&](int ibuf, int obuf) {
        float2 rin[K];
#pragma unroll
        for (int k = 0; k < K; ++k)
            rin[k] = stIn[ibuf][k][lane];
#pragma unroll
        for (int k = 0; k < K; ++k) {
            const float Pt = rin[k].x, PET_t = rin[k].y;
            const float PETmP = PET_t - Pt;              // input-only, off-chain
            const float capD  = fmaxf(wdm, WD);
            // evap cascade; M0 = P-EU = min(PET-P, WU) (exact)
            const float M0 = fminf(PETmP, WU);
            const float D  = fmaxf(PETmP - WU, 0.f);
            const float ELwet = D * wlinvC;
            const float CD    = C * D;
            const float ELdry = fminf(CD, WL);
            const float EL    = med3(fmaf(wrC, ELwet - ELdry, ELdry), 0.f, WL);
            const float ED    = med3(fmaf(-C, EL, CD), 0.f, WD);
            const float SUME  = (M0 + EL) + ED;          // = E - P
            const float PE    = fmaxf(-SUME, 0.f);
            const float E     = Pt + SUME;
            const float W     = (WU + WL) + WD;
            // runoff: ONE pow on the carried cycle (pw1 is carried)
            const float omr   = fmaxf(fmaf(-PE, inv_WMM, pw1), 0.f);
            const float powr  = fpow(omr, expB);
            const float R_per = fmaxf(fmaf(WM, powr, PE + (W - WM)), 0.f);
            // dry-path pow: W' = W - SUME known right after SUME -> PARALLEL
            const float bwd  = fmaxf(fmaf(-(W - SUME), inv_WM, 1.f), PRECS);
            const float pw1d = fpow(bwd, invB);
            // wet identity: W' = WM*(1-powr) exactly => pw1' = omr (floored)
            pw1 = (SUME < 0.f) ? fmaxf(omr, powPRECS) : pw1d;
            // unified signed-residual cascade (exact for both signs of dW)
            const float c0  = (WU - SUME) - R_per;
            const float WUn = med3(c0, 0.f, WUM);
            const float c1  = WL + (c0 - WUn);
            const float WLn = med3(c1, 0.f, WLM);
            const float c2  = WD + (c1 - WLn);
            const float WDn = med3(c2, 0.f, capD);
            WU = WUn; WL = WLn; WD = WDn;
            // step-tail hoists (off next step's front)
            const float weN = fmaxf(WLn - CWLM, 0.f);
            wrC    = weN * frcp(1.f + weN);
            wlinvC = WLn * inv_WLM;
            stA[obuf][k][lane] = make_float4(PE, R_per, E, 0.f);
        }
    };

    auto BSTEP = [&](int abuf, int fbuf) {
        float4 ra[K], rg[K];
#pragma unroll
        for (int k = 0; k < K; ++k) ra[k] = stA[abuf][k][lane];
#pragma unroll
        for (int k = 0; k < K; ++k) rg[k] = stFR[fbuf][k][lane];
#pragma unroll
        for (int k = 0; k < K; ++k) {
            const float PE = ra[k].x, R_per = ra[k].y;
            const float FR = rg[k].x, iFR = rg[k].y;
            const float giFR = rg[k].z, r2 = rg[k].w;
            // off-chain early values
            const float RpiFR = R_per * iFR;
            const float corr  = RpiFR - PE;
            // carried cycle: Snc -> ratio_s -> u -> om2 -> q -> T -> med3 -> Snc'
            const float S_eq    = fminf(Snc * giFR, SM);
            const float ratio_s = fmaxf(fmaf(-Snc, r2, 1.f), eps2);
            const float u   = fpow(ratio_s, invEX);
            const float om2 = fmaxf(fmaf(-PE, inv_SMM, u), 0.f);
            const float q   = fpow(om2, expEX);
            const float T   = fmaf(-SM, q, SM - S_eq);
            const float mq  = med3(T + corr, 0.f, RpiFR);
            const float Sn  = S_eq + mq;
            // RS output only (off the carry)
            const float base = (PE - SM) + S_eq;
            const float RS = med3(fmaf(SM, q, base) * FR, 0.f, R_per);
            stB[fbuf][k][lane] = make_float4(RS, FR * Sn, ra[k].z, 0.f);
            Snc = Sn;
        }
    };

    auto CISSUE = [&](int blk) {
#pragma unroll
        for (int k = 0; k < K; ++k) {
            int t = blk * K + k;
            t = (t < Nstep) ? t : Nstep - 1;
            const float* xq = xg + (size_t)t * xstride;
            Pr[k] = xq[0];
            Er[k] = xq[2];
        }
    };
    auto CFR = [&](int abuf, int fbuf) {
        // candidates + select-scan resolve (pure function of PE/R_per):
        // rcp(min(aa,1)+PRECS) == max(rcp(aa+PRECS), inv1p)
#pragma unroll
        for (int k = 0; k < K; ++k) {
            const float4 ra = stA[abuf][k][lane];
            const float gk = oneK * FRc;             // g for step k: oneK*FR_{k-1}
            const float q  = frcp(ra.x + PRECS);
            const float aa = ra.y * q;
            const float FRn  = fminf(aa, 1.f);
            const float iFRn = fmaxf(frcp(aa + PRECS), inv1p);
            const bool wet = ra.x > 0.f;
            FRc  = wet ? FRn  : FRc;
            iFRc = wet ? iFRn : iFRc;
            const float giFR = gk * iFRc;
            const float r2   = giFR * inv_SM;
            stFR[fbuf][k][lane] = make_float4(FRc, iFRc, giFR, r2);
        }
    };
    auto CWRITE = [&](int buf) {
#pragma unroll
        for (int k = 0; k < K; ++k)
            stIn[buf][k][lane] = make_float2(Pr[k], Er[k] * KE);
    };

    auto DSTEP = [&](int bbuf, int blk) {
        float4 rb[K];
#pragma unroll
        for (int k = 0; k < K; ++k) rb[k] = stB[bbuf][k][lane];
        const int t0 = blk * K;
#pragma unroll
        for (int k = 0; k < K; ++k) {
            // QI/QG EMA: RI = KI*FR*Sn = KI*rb.y, RG = KG*rb.y
            QI = fmaf(CI, QI, cKI * rb[k].y);
            QG = fmaf(CG, QG, cKG * rb[k].y);
            const float u0 = rsum8(rb[k].x);
            const float u1 = rsum8(QI);
            const float u2 = rsum8(QG);
            const float u3 = rsum8(rb[k].z);
            const float v = fmaf(u0, wa, fmaf(u1, wb, fmaf(u2, wc, u3 * wd)));
            if (t0 + k < Nstep)
                outp[(size_t)(t0 + k) * ostr] = v;
        }
    };

    // ---------------- phase loop ----------------
    // phase p (0..25):
    //   A: block p        (p < NBLK):      stIn[p&1] -> stA[p&3]
    //   B: block p-2      (2<=p<NBLK+2):   stA[(p-2)&3] + stFR[(p-2)&1] -> stB[(p-2)&1]
    //   C: load block p+1 (p+1 < NBLK) -> stIn[(p+1)&1];
    //      FR block p-1   (1<=p<NBLK+1):   stA[(p-1)&3] -> stFR[(p-1)&1]
    //   D: block p-3      (p>=3):          stB[(p-3)&1] -> out
    if (wid == 2) { CISSUE(0); CWRITE(0); }   // prime block 0
    __syncthreads();

#pragma unroll 1
    for (int ph = 0; ph < NPH; ++ph) {
        if (wid == 0) {
            if (ph < NBLK) ASTEP(ph & 1, ph & 3);
        } else if (wid == 1) {
            if (ph >= 2 && ph < NBLK + 2) BSTEP((ph - 2) & 3, (ph - 2) & 1);
        } else if (wid == 2) {
            const bool ld = (ph + 1 < NBLK);
            if (ld) CISSUE(ph + 1);                       // issue loads first...
            if (ph >= 1 && ph < NBLK + 1)
                CFR((ph - 1) & 3, (ph - 1) & 1);          // ...hide latency under FR
            if (ld) CWRITE((ph + 1) & 1);
        } else {
            if (ph >= 3) DSTEP((ph - 3) & 1, ph - 3);
        }
        __syncthreads();
    }
}

extern "C" void kernel_launch(void* const* d_in, const int* in_sizes, int n_in,
                              void* d_out, int out_size, void* d_ws, size_t ws_size,
                              hipStream_t stream) {
    const float* x   = (const float*)d_in[0];
    const float* prm = (const float*)d_in[1];
    float* out = (float*)d_out;
    xaj_kernel<<<250, 256, 0, stream>>>(x, prm, out);
}